// Round 6
// baseline (373.879 us; speedup 1.0000x reference)
//
#include <hip/hip_runtime.h>

#define NXD   512
#define NYD   512
#define CD    64
#define BD    4
#define GRIDC (NXD * NYD)          // 262144 cells per frame (NZ==1)

// map encoding: bits[0:16] = row+1 (<=65536), bits[17:22] = npts (<=32), bit23 = selected
#define ROW_MASK   0x1FFFF
#define NPTS_SHIFT 17
#define SEL_FLAG   (1 << 23)

// 4096 cells per block, 16 per thread
#define CELLS_PER_BLOCK 4096
#define CHUNKS_PER_PLANE (GRIDC / CELLS_PER_BLOCK)           // 64
#define SPATIAL_BLOCKS   (BD * CD * CHUNKS_PER_PLANE)        // 16384
#define META_BLOCKS      (BD * GRIDC / CELLS_PER_BLOCK)      // 256

typedef float f32x4 __attribute__((ext_vector_type(4)));
typedef int   i32x4 __attribute__((ext_vector_type(4)));

// ---------------- fused path ----------------

// atomicOr so the pillar write and the selected-flag write compose in any order.
// Tail threads [M+K, M+K+64) zero the 256B zero-gather page.
__global__ void build_map_kernel(const int* __restrict__ coords,
                                 const int* __restrict__ sel,
                                 const int* __restrict__ npts,
                                 int* __restrict__ map,
                                 float* __restrict__ zerobuf,
                                 int M, int K) {
    int i = blockIdx.x * blockDim.x + threadIdx.x;
    if (i < M) {
        i32x4 cr = *reinterpret_cast<const i32x4*>(coords + 4 * i);
        int cell = cr.x * GRIDC + cr.y + cr.z * NXD + cr.w;
        atomicOr(map + cell, (i + 1) | (npts[i] << NPTS_SHIFT));
    } else if (i < M + K) {
        int r = sel[i - M];
        i32x4 cr = *reinterpret_cast<const i32x4*>(coords + 4 * r);
        int cell = cr.x * GRIDC + cr.y + cr.z * NXD + cr.w;
        atomicOr(map + cell, SEL_FLAG);
    } else if (i < M + K + CD) {
        zerobuf[i - (M + K)] = 0.0f;
    }
}

// LINEAR-store one-pass fill. Spatial block bid owns the contiguous 16KB
// output span [bid*4096, +4096) floats == (frame b, channel c, 4096 cells).
// chunk is the fastest-varying field of bid, so same-chunk blocks across all
// 64 channels land on the same XCD (bid deltas are multiples of 64*... = 0 mod 8
// is NOT needed: deltas of 64 blocks; 64 % 8 == 0) -> map slice + feats rows
// are fetched once per XCD. Tail blocks write the three meta maps.
__global__ __launch_bounds__(256) void linear_fill_kernel(
        const float* __restrict__ feats,
        const int*   __restrict__ map,
        const float* __restrict__ zerobuf,
        float* __restrict__ out) {
    const int bid = blockIdx.x;
    const int t   = threadIdx.x;

    if (bid < SPATIAL_BLOCKS) {
        // bid = ((b*64 + c) * 64 + chunk)
        const int b     = bid >> 12;
        const int c     = (bid >> 6) & 63;
        const int chunk = bid & 63;
        const int cell0 = chunk * CELLS_PER_BLOCK + t * 16;   // within frame

        const int* mp = map + (size_t)b * GRIDC + cell0;
        // 4 independent 16B map loads
        i32x4 m0 = *reinterpret_cast<const i32x4*>(mp + 0);
        i32x4 m1 = *reinterpret_cast<const i32x4*>(mp + 4);
        i32x4 m2 = *reinterpret_cast<const i32x4*>(mp + 8);
        i32x4 m3 = *reinterpret_cast<const i32x4*>(mp + 12);
        int rows[16] = {m0.x, m0.y, m0.z, m0.w, m1.x, m1.y, m1.z, m1.w,
                        m2.x, m2.y, m2.z, m2.w, m3.x, m3.y, m3.z, m3.w};

        // 16 independent branch-free gathers (zerobuf for unselected)
        float g[16];
        #pragma unroll
        for (int j = 0; j < 16; ++j) {
            int m = rows[j];
            const float* p = (m & SEL_FLAG)
                ? (feats + ((size_t)((m & ROW_MASK) - 1) << 6))
                : zerobuf;
            g[j] = p[c];
        }

        float* dst = out + (size_t)bid * CELLS_PER_BLOCK + t * 16;
        #pragma unroll
        for (int q = 0; q < 4; ++q) {
            f32x4 v;
            v[0] = g[4 * q + 0]; v[1] = g[4 * q + 1];
            v[2] = g[4 * q + 2]; v[3] = g[4 * q + 3];
            __builtin_nontemporal_store(v, reinterpret_cast<f32x4*>(dst + 4 * q));
        }
    } else {
        // meta: occ / dens / pnum, each [B][GRIDC], after the spatial region
        const int mid = bid - SPATIAL_BLOCKS;                    // 0..255
        const size_t cbase = (size_t)mid * CELLS_PER_BLOCK + t * 16;

        const int* mp = map + cbase;
        i32x4 m0 = *reinterpret_cast<const i32x4*>(mp + 0);
        i32x4 m1 = *reinterpret_cast<const i32x4*>(mp + 4);
        i32x4 m2 = *reinterpret_cast<const i32x4*>(mp + 8);
        i32x4 m3 = *reinterpret_cast<const i32x4*>(mp + 12);
        int rows[16] = {m0.x, m0.y, m0.z, m0.w, m1.x, m1.y, m1.z, m1.w,
                        m2.x, m2.y, m2.z, m2.w, m3.x, m3.y, m3.z, m3.w};

        const size_t spatial_elems = (size_t)BD * CD * GRIDC;
        const size_t map_elems     = (size_t)BD * GRIDC;
        float* __restrict__ occ  = out + spatial_elems;
        float* __restrict__ dens = occ + map_elems;
        float* __restrict__ pnum = dens + map_elems;

        #pragma unroll
        for (int q = 0; q < 4; ++q) {
            f32x4 o, d, pn;
            #pragma unroll
            for (int j = 0; j < 4; ++j) {
                int m = rows[4 * q + j];
                if (m != 0) {
                    float n = (float)((m >> NPTS_SHIFT) & 63);
                    o[j] = 1.0f;
                    d[j] = n * (1.0f / 32.0f);
                    pn[j] = n;
                } else {
                    o[j] = 0.f; d[j] = 0.f; pn[j] = 0.f;
                }
            }
            __builtin_nontemporal_store(o,  reinterpret_cast<f32x4*>(occ  + cbase + 4 * q));
            __builtin_nontemporal_store(d,  reinterpret_cast<f32x4*>(dens + cbase + 4 * q));
            __builtin_nontemporal_store(pn, reinterpret_cast<f32x4*>(pnum + cbase + 4 * q));
        }
    }
}

// ---------------- fallback path (used only if ws too small) ----------------

__global__ void scatter_meta_kernel(const int* __restrict__ coords,
                                    const int* __restrict__ npts,
                                    float* __restrict__ occ,
                                    float* __restrict__ dens,
                                    float* __restrict__ pnum,
                                    int M) {
    int i = blockIdx.x * blockDim.x + threadIdx.x;
    if (i >= M) return;
    int b = coords[4 * i + 0];
    int z = coords[4 * i + 1];
    int y = coords[4 * i + 2];
    int x = coords[4 * i + 3];
    int cell = b * GRIDC + z + y * NXD + x;
    float n = (float)npts[i];
    occ[cell]  = 1.0f;
    dens[cell] = n * (1.0f / 32.0f);
    pnum[cell] = n;
}

__global__ void scatter_spatial_kernel(const float* __restrict__ feats,
                                       const int* __restrict__ coords,
                                       const int* __restrict__ sel,
                                       float* __restrict__ spatial,
                                       int K) {
    int group = blockIdx.x * (blockDim.x >> 6) + (threadIdx.x >> 6);
    int c     = threadIdx.x & 63;
    if (group >= K) return;
    int row = sel[group];
    int b = coords[4 * row + 0];
    int z = coords[4 * row + 1];
    int y = coords[4 * row + 2];
    int x = coords[4 * row + 3];
    int cell = z + y * NXD + x;
    float v = feats[(size_t)row * CD + c];
    spatial[(size_t)b * ((size_t)CD * GRIDC) + (size_t)c * GRIDC + (size_t)cell] = v;
}

extern "C" void kernel_launch(void* const* d_in, const int* in_sizes, int n_in,
                              void* d_out, int out_size, void* d_ws, size_t ws_size,
                              hipStream_t stream) {
    const float* feats  = (const float*)d_in[0];  // [M, 64] f32
    const int*   coords = (const int*)d_in[1];    // [M, 4]  (b,z,y,x)
    const int*   npts   = (const int*)d_in[2];    // [M]
    const int*   sel    = (const int*)d_in[3];    // [K]

    const int M = in_sizes[2];
    const int K = in_sizes[3];

    float* out = (float*)d_out;
    const size_t map_bytes  = (size_t)BD * GRIDC * sizeof(int);  // 4 MB
    const size_t zero_bytes = CD * sizeof(float);                // 256 B

    if (ws_size >= map_bytes + zero_bytes) {
        int* map = (int*)d_ws;
        float* zerobuf = (float*)((char*)d_ws + map_bytes);
        (void)hipMemsetAsync(map, 0, map_bytes, stream);
        build_map_kernel<<<(M + K + CD + 255) / 256, 256, 0, stream>>>(
            coords, sel, npts, map, zerobuf, M, K);
        linear_fill_kernel<<<SPATIAL_BLOCKS + META_BLOCKS, 256, 0, stream>>>(
            feats, map, zerobuf, out);
    } else {
        // fallback: memset + scatter
        size_t spatial_elems = (size_t)BD * CD * GRIDC;
        size_t map_elems     = (size_t)BD * GRIDC;
        float* occ  = out + spatial_elems;
        float* dens = occ + map_elems;
        float* pnum = dens + map_elems;
        (void)hipMemsetAsync(d_out, 0, (size_t)out_size * sizeof(float), stream);
        scatter_meta_kernel<<<(M + 255) / 256, 256, 0, stream>>>(
            coords, npts, occ, dens, pnum, M);
        scatter_spatial_kernel<<<(K + 3) / 4, 256, 0, stream>>>(
            feats, coords, sel, out, K);
    }
}

// Round 7
// 64.965 us; speedup vs baseline: 5.7551x; 5.7551x over previous
//
#include <hip/hip_runtime.h>

#define NXD   512
#define NYD   512
#define CD    64
#define BD    4
#define GRIDC (NXD * NYD)          // 262144 cells per frame (NZ==1)

// map encoding: bits[0:16] = row+1 (<=65536), bits[17:22] = npts (<=32), bit23 = selected
#define ROW_MASK   0x1FFFF
#define NPTS_SHIFT 17
#define SEL_FLAG   (1 << 23)

// 4096 cells per block, processed as 4 wave-coalesced passes of 1024 cells
#define CELLS_PER_BLOCK 4096
#define CHUNKS_PER_PLANE (GRIDC / CELLS_PER_BLOCK)           // 64
#define SPATIAL_BLOCKS   (BD * CD * CHUNKS_PER_PLANE)        // 16384
#define META_BLOCKS      (BD * GRIDC / CELLS_PER_BLOCK)      // 256

typedef float f32x4 __attribute__((ext_vector_type(4)));
typedef int   i32x4 __attribute__((ext_vector_type(4)));

// ---------------- fused path ----------------

// atomicOr so the pillar write and the selected-flag write compose in any order.
// Tail threads [M+K, M+K+64) zero the 256B zero-gather page.
__global__ void build_map_kernel(const int* __restrict__ coords,
                                 const int* __restrict__ sel,
                                 const int* __restrict__ npts,
                                 int* __restrict__ map,
                                 float* __restrict__ zerobuf,
                                 int M, int K) {
    int i = blockIdx.x * blockDim.x + threadIdx.x;
    if (i < M) {
        i32x4 cr = *reinterpret_cast<const i32x4*>(coords + 4 * i);
        int cell = cr.x * GRIDC + cr.y + cr.z * NXD + cr.w;
        atomicOr(map + cell, (i + 1) | (npts[i] << NPTS_SHIFT));
    } else if (i < M + K) {
        int r = sel[i - M];
        i32x4 cr = *reinterpret_cast<const i32x4*>(coords + 4 * r);
        int cell = cr.x * GRIDC + cr.y + cr.z * NXD + cr.w;
        atomicOr(map + cell, SEL_FLAG);
    } else if (i < M + K + CD) {
        zerobuf[i - (M + K)] = 0.0f;
    }
}

// LINEAR-store one-pass fill. Spatial block bid owns the contiguous 16KB
// output span [bid*4096, +4096) floats == (frame b, channel c, 4096 cells),
// processed as 4 passes; pass p covers cells p*1024 + t*4 so every map load
// and NT store is wave-contiguous (1KB per wave-instruction). The 4 passes
// are independent chains (MLP). Tail blocks write the three meta maps.
__global__ __launch_bounds__(256) void linear_fill_kernel(
        const float* __restrict__ feats,
        const int*   __restrict__ map,
        const float* __restrict__ zerobuf,
        float* __restrict__ out) {
    const int bid = blockIdx.x;
    const int t   = threadIdx.x;

    if (bid < SPATIAL_BLOCKS) {
        // bid = ((b*64 + c) * 64 + chunk)
        const int b     = bid >> 12;
        const int c     = (bid >> 6) & 63;
        const int chunk = bid & 63;
        const int cell0 = chunk * CELLS_PER_BLOCK;            // within frame

        const int* mp = map + (size_t)b * GRIDC + cell0 + t * 4;
        // 4 independent coalesced 16B map loads (stride 4KB between passes)
        i32x4 m0 = *reinterpret_cast<const i32x4*>(mp + 0 * 1024);
        i32x4 m1 = *reinterpret_cast<const i32x4*>(mp + 1 * 1024);
        i32x4 m2 = *reinterpret_cast<const i32x4*>(mp + 2 * 1024);
        i32x4 m3 = *reinterpret_cast<const i32x4*>(mp + 3 * 1024);
        int rows[16] = {m0.x, m0.y, m0.z, m0.w, m1.x, m1.y, m1.z, m1.w,
                        m2.x, m2.y, m2.z, m2.w, m3.x, m3.y, m3.z, m3.w};

        // 16 independent branch-free gathers (zerobuf for unselected)
        float g[16];
        #pragma unroll
        for (int j = 0; j < 16; ++j) {
            int m = rows[j];
            const float* p = (m & SEL_FLAG)
                ? (feats + ((size_t)((m & ROW_MASK) - 1) << 6))
                : zerobuf;
            g[j] = p[c];
        }

        float* dst = out + (size_t)bid * CELLS_PER_BLOCK + t * 4;
        #pragma unroll
        for (int q = 0; q < 4; ++q) {
            f32x4 v;
            v[0] = g[4 * q + 0]; v[1] = g[4 * q + 1];
            v[2] = g[4 * q + 2]; v[3] = g[4 * q + 3];
            __builtin_nontemporal_store(
                v, reinterpret_cast<f32x4*>(dst + q * 1024));
        }
    } else {
        // meta: occ / dens / pnum, each [B][GRIDC], after the spatial region
        const int mid = bid - SPATIAL_BLOCKS;                    // 0..255
        const size_t cbase = (size_t)mid * CELLS_PER_BLOCK + t * 4;

        const int* mp = map + cbase;
        i32x4 m0 = *reinterpret_cast<const i32x4*>(mp + 0 * 1024);
        i32x4 m1 = *reinterpret_cast<const i32x4*>(mp + 1 * 1024);
        i32x4 m2 = *reinterpret_cast<const i32x4*>(mp + 2 * 1024);
        i32x4 m3 = *reinterpret_cast<const i32x4*>(mp + 3 * 1024);
        int rows[16] = {m0.x, m0.y, m0.z, m0.w, m1.x, m1.y, m1.z, m1.w,
                        m2.x, m2.y, m2.z, m2.w, m3.x, m3.y, m3.z, m3.w};

        const size_t spatial_elems = (size_t)BD * CD * GRIDC;
        const size_t map_elems     = (size_t)BD * GRIDC;
        float* __restrict__ occ  = out + spatial_elems;
        float* __restrict__ dens = occ + map_elems;
        float* __restrict__ pnum = dens + map_elems;

        #pragma unroll
        for (int q = 0; q < 4; ++q) {
            f32x4 o, d, pn;
            #pragma unroll
            for (int j = 0; j < 4; ++j) {
                int m = rows[4 * q + j];
                if (m != 0) {
                    float n = (float)((m >> NPTS_SHIFT) & 63);
                    o[j] = 1.0f;
                    d[j] = n * (1.0f / 32.0f);
                    pn[j] = n;
                } else {
                    o[j] = 0.f; d[j] = 0.f; pn[j] = 0.f;
                }
            }
            __builtin_nontemporal_store(o,  reinterpret_cast<f32x4*>(occ  + cbase + q * 1024));
            __builtin_nontemporal_store(d,  reinterpret_cast<f32x4*>(dens + cbase + q * 1024));
            __builtin_nontemporal_store(pn, reinterpret_cast<f32x4*>(pnum + cbase + q * 1024));
        }
    }
}

// ---------------- fallback path (used only if ws too small) ----------------

__global__ void scatter_meta_kernel(const int* __restrict__ coords,
                                    const int* __restrict__ npts,
                                    float* __restrict__ occ,
                                    float* __restrict__ dens,
                                    float* __restrict__ pnum,
                                    int M) {
    int i = blockIdx.x * blockDim.x + threadIdx.x;
    if (i >= M) return;
    int b = coords[4 * i + 0];
    int z = coords[4 * i + 1];
    int y = coords[4 * i + 2];
    int x = coords[4 * i + 3];
    int cell = b * GRIDC + z + y * NXD + x;
    float n = (float)npts[i];
    occ[cell]  = 1.0f;
    dens[cell] = n * (1.0f / 32.0f);
    pnum[cell] = n;
}

__global__ void scatter_spatial_kernel(const float* __restrict__ feats,
                                       const int* __restrict__ coords,
                                       const int* __restrict__ sel,
                                       float* __restrict__ spatial,
                                       int K) {
    int group = blockIdx.x * (blockDim.x >> 6) + (threadIdx.x >> 6);
    int c     = threadIdx.x & 63;
    if (group >= K) return;
    int row = sel[group];
    int b = coords[4 * row + 0];
    int z = coords[4 * row + 1];
    int y = coords[4 * row + 2];
    int x = coords[4 * row + 3];
    int cell = z + y * NXD + x;
    float v = feats[(size_t)row * CD + c];
    spatial[(size_t)b * ((size_t)CD * GRIDC) + (size_t)c * GRIDC + (size_t)cell] = v;
}

extern "C" void kernel_launch(void* const* d_in, const int* in_sizes, int n_in,
                              void* d_out, int out_size, void* d_ws, size_t ws_size,
                              hipStream_t stream) {
    const float* feats  = (const float*)d_in[0];  // [M, 64] f32
    const int*   coords = (const int*)d_in[1];    // [M, 4]  (b,z,y,x)
    const int*   npts   = (const int*)d_in[2];    // [M]
    const int*   sel    = (const int*)d_in[3];    // [K]

    const int M = in_sizes[2];
    const int K = in_sizes[3];

    float* out = (float*)d_out;
    const size_t map_bytes  = (size_t)BD * GRIDC * sizeof(int);  // 4 MB
    const size_t zero_bytes = CD * sizeof(float);                // 256 B

    if (ws_size >= map_bytes + zero_bytes) {
        int* map = (int*)d_ws;
        float* zerobuf = (float*)((char*)d_ws + map_bytes);
        (void)hipMemsetAsync(map, 0, map_bytes, stream);
        build_map_kernel<<<(M + K + CD + 255) / 256, 256, 0, stream>>>(
            coords, sel, npts, map, zerobuf, M, K);
        linear_fill_kernel<<<SPATIAL_BLOCKS + META_BLOCKS, 256, 0, stream>>>(
            feats, map, zerobuf, out);
    } else {
        // fallback: memset + scatter
        size_t spatial_elems = (size_t)BD * CD * GRIDC;
        size_t map_elems     = (size_t)BD * GRIDC;
        float* occ  = out + spatial_elems;
        float* dens = occ + map_elems;
        float* pnum = dens + map_elems;
        (void)hipMemsetAsync(d_out, 0, (size_t)out_size * sizeof(float), stream);
        scatter_meta_kernel<<<(M + 255) / 256, 256, 0, stream>>>(
            coords, npts, occ, dens, pnum, M);
        scatter_spatial_kernel<<<(K + 3) / 4, 256, 0, stream>>>(
            feats, coords, sel, out, K);
    }
}

// Round 8
// 63.633 us; speedup vs baseline: 5.8755x; 1.0209x over previous
//
#include <hip/hip_runtime.h>

#define NXD   512
#define NYD   512
#define CD    64
#define BD    4
#define GRIDC (NXD * NYD)          // 262144 cells per frame (NZ==1)

// map encoding: bits[0:16] = row+1 (<=65536), bits[17:22] = npts (<=32), bit23 = selected
#define ROW_MASK   0x1FFFF
#define NPTS_SHIFT 17
#define SEL_FLAG   (1 << 23)

// 1024 cells per block (R5 structure — proven best)
#define CELLS_PER_BLOCK 1024
#define CHUNKS_PER_PLANE (GRIDC / CELLS_PER_BLOCK)           // 256
#define SPATIAL_BLOCKS   (BD * CD * CHUNKS_PER_PLANE)        // 65536
#define META_BLOCKS      (BD * GRIDC / CELLS_PER_BLOCK)      // 1024

typedef float f32x4 __attribute__((ext_vector_type(4)));
typedef int   i32x4 __attribute__((ext_vector_type(4)));

// ---------------- fused path ----------------

// atomicOr so the pillar write and the selected-flag write compose in any order.
// Tail threads [M+K, M+K+64) zero the 256B zero-gather page.
__global__ void build_map_kernel(const int* __restrict__ coords,
                                 const int* __restrict__ sel,
                                 const int* __restrict__ npts,
                                 int* __restrict__ map,
                                 float* __restrict__ zerobuf,
                                 int M, int K) {
    int i = blockIdx.x * blockDim.x + threadIdx.x;
    if (i < M) {
        i32x4 cr = *reinterpret_cast<const i32x4*>(coords + 4 * i);
        int cell = cr.x * GRIDC + cr.y + cr.z * NXD + cr.w;
        atomicOr(map + cell, (i + 1) | (npts[i] << NPTS_SHIFT));
    } else if (i < M + K) {
        int r = sel[i - M];
        i32x4 cr = *reinterpret_cast<const i32x4*>(coords + 4 * r);
        int cell = cr.x * GRIDC + cr.y + cr.z * NXD + cr.w;
        atomicOr(map + cell, SEL_FLAG);
    } else if (i < M + K + CD) {
        zerobuf[i - (M + K)] = 0.0f;
    }
}

// LINEAR-store one-pass fill (R5 structure). Meta blocks are at the FRONT of
// the grid so their 12MB don't form a serial tail. Spatial block sbid owns the
// contiguous 4KB output span [sbid*1024, +1024) floats == (frame b, channel c,
// 1024 cells); thread t handles cells t*4 (wave-contiguous loads and stores).
// Same-chunk blocks across channels differ by multiples of 256 blocks
// (and META_BLOCKS=1024), both ≡ 0 mod 8 -> same XCD -> map slice + feats
// rows fetched ~once per XCD. Regular (cached) stores — A/B vs NT.
__global__ __launch_bounds__(256) void linear_fill_kernel(
        const float* __restrict__ feats,
        const int*   __restrict__ map,
        const float* __restrict__ zerobuf,
        float* __restrict__ out) {
    const int bid = blockIdx.x;
    const int t   = threadIdx.x;

    if (bid >= META_BLOCKS) {
        const int sbid = bid - META_BLOCKS;
        // sbid = ((b*64 + c) * 256 + chunk)
        const int b     = sbid >> 14;
        const int c     = (sbid >> 8) & 63;
        const int chunk = sbid & 255;
        const int cell0 = chunk * CELLS_PER_BLOCK + t * 4;    // within frame

        const i32x4 m4 = *reinterpret_cast<const i32x4*>(
            map + (size_t)b * GRIDC + cell0);
        const int rows[4] = {m4.x, m4.y, m4.z, m4.w};

        f32x4 v;
        #pragma unroll
        for (int j = 0; j < 4; ++j) {
            int m = rows[j];
            const float* p = (m & SEL_FLAG)
                ? (feats + ((size_t)((m & ROW_MASK) - 1) << 6))
                : zerobuf;
            v[j] = p[c];
        }
        *reinterpret_cast<f32x4*>(out + (size_t)sbid * CELLS_PER_BLOCK + t * 4) = v;
    } else {
        // meta: occ / dens / pnum, each [B][GRIDC], after the spatial region
        const size_t cbase = (size_t)bid * CELLS_PER_BLOCK + t * 4;

        const i32x4 m4 = *reinterpret_cast<const i32x4*>(map + cbase);
        const int rows[4] = {m4.x, m4.y, m4.z, m4.w};

        const size_t spatial_elems = (size_t)BD * CD * GRIDC;
        const size_t map_elems     = (size_t)BD * GRIDC;
        float* __restrict__ occ  = out + spatial_elems;
        float* __restrict__ dens = occ + map_elems;
        float* __restrict__ pnum = dens + map_elems;

        f32x4 o, d, pn;
        #pragma unroll
        for (int j = 0; j < 4; ++j) {
            int m = rows[j];
            if (m != 0) {
                float n = (float)((m >> NPTS_SHIFT) & 63);
                o[j] = 1.0f;
                d[j] = n * (1.0f / 32.0f);
                pn[j] = n;
            } else {
                o[j] = 0.f; d[j] = 0.f; pn[j] = 0.f;
            }
        }
        *reinterpret_cast<f32x4*>(occ  + cbase) = o;
        *reinterpret_cast<f32x4*>(dens + cbase) = d;
        *reinterpret_cast<f32x4*>(pnum + cbase) = pn;
    }
}

// ---------------- fallback path (used only if ws too small) ----------------

__global__ void scatter_meta_kernel(const int* __restrict__ coords,
                                    const int* __restrict__ npts,
                                    float* __restrict__ occ,
                                    float* __restrict__ dens,
                                    float* __restrict__ pnum,
                                    int M) {
    int i = blockIdx.x * blockDim.x + threadIdx.x;
    if (i >= M) return;
    int b = coords[4 * i + 0];
    int z = coords[4 * i + 1];
    int y = coords[4 * i + 2];
    int x = coords[4 * i + 3];
    int cell = b * GRIDC + z + y * NXD + x;
    float n = (float)npts[i];
    occ[cell]  = 1.0f;
    dens[cell] = n * (1.0f / 32.0f);
    pnum[cell] = n;
}

__global__ void scatter_spatial_kernel(const float* __restrict__ feats,
                                       const int* __restrict__ coords,
                                       const int* __restrict__ sel,
                                       float* __restrict__ spatial,
                                       int K) {
    int group = blockIdx.x * (blockDim.x >> 6) + (threadIdx.x >> 6);
    int c     = threadIdx.x & 63;
    if (group >= K) return;
    int row = sel[group];
    int b = coords[4 * row + 0];
    int z = coords[4 * row + 1];
    int y = coords[4 * row + 2];
    int x = coords[4 * row + 3];
    int cell = z + y * NXD + x;
    float v = feats[(size_t)row * CD + c];
    spatial[(size_t)b * ((size_t)CD * GRIDC) + (size_t)c * GRIDC + (size_t)cell] = v;
}

extern "C" void kernel_launch(void* const* d_in, const int* in_sizes, int n_in,
                              void* d_out, int out_size, void* d_ws, size_t ws_size,
                              hipStream_t stream) {
    const float* feats  = (const float*)d_in[0];  // [M, 64] f32
    const int*   coords = (const int*)d_in[1];    // [M, 4]  (b,z,y,x)
    const int*   npts   = (const int*)d_in[2];    // [M]
    const int*   sel    = (const int*)d_in[3];    // [K]

    const int M = in_sizes[2];
    const int K = in_sizes[3];

    float* out = (float*)d_out;
    const size_t map_bytes  = (size_t)BD * GRIDC * sizeof(int);  // 4 MB
    const size_t zero_bytes = CD * sizeof(float);                // 256 B

    if (ws_size >= map_bytes + zero_bytes) {
        int* map = (int*)d_ws;
        float* zerobuf = (float*)((char*)d_ws + map_bytes);
        (void)hipMemsetAsync(map, 0, map_bytes, stream);
        build_map_kernel<<<(M + K + CD + 255) / 256, 256, 0, stream>>>(
            coords, sel, npts, map, zerobuf, M, K);
        linear_fill_kernel<<<SPATIAL_BLOCKS + META_BLOCKS, 256, 0, stream>>>(
            feats, map, zerobuf, out);
    } else {
        // fallback: memset + scatter
        size_t spatial_elems = (size_t)BD * CD * GRIDC;
        size_t map_elems     = (size_t)BD * GRIDC;
        float* occ  = out + spatial_elems;
        float* dens = occ + map_elems;
        float* pnum = dens + map_elems;
        (void)hipMemsetAsync(d_out, 0, (size_t)out_size * sizeof(float), stream);
        scatter_meta_kernel<<<(M + 255) / 256, 256, 0, stream>>>(
            coords, npts, occ, dens, pnum, M);
        scatter_spatial_kernel<<<(K + 3) / 4, 256, 0, stream>>>(
            feats, coords, sel, out, K);
    }
}

// Round 9
// 59.235 us; speedup vs baseline: 6.3118x; 1.0743x over previous
//
#include <hip/hip_runtime.h>

#define NXD   512
#define NYD   512
#define CD    64
#define BD    4
#define GRIDC (NXD * NYD)          // 262144 cells per frame (NZ==1)

// map encoding: bits[0:16] = row+1 (<=65536), bits[17:22] = npts (<=32), bit23 = selected
#define ROW_MASK   0x1FFFF
#define NPTS_SHIFT 17
#define SEL_FLAG   (1 << 23)

// 1024 cells per block (R5 structure — proven best)
#define CELLS_PER_BLOCK 1024
#define CHUNKS_PER_PLANE (GRIDC / CELLS_PER_BLOCK)           // 256
#define SPATIAL_BLOCKS   (BD * CD * CHUNKS_PER_PLANE)        // 65536
#define META_BLOCKS      (BD * GRIDC / CELLS_PER_BLOCK)      // 1024

typedef float f32x4 __attribute__((ext_vector_type(4)));
typedef int   i32x4 __attribute__((ext_vector_type(4)));

// ---------------- fused path ----------------

// atomicOr so the pillar write and the selected-flag write compose in any order.
// Tail threads [M+K, M+K+64) zero the 256B zero-gather page.
__global__ void build_map_kernel(const int* __restrict__ coords,
                                 const int* __restrict__ sel,
                                 const int* __restrict__ npts,
                                 int* __restrict__ map,
                                 float* __restrict__ zerobuf,
                                 int M, int K) {
    int i = blockIdx.x * blockDim.x + threadIdx.x;
    if (i < M) {
        i32x4 cr = *reinterpret_cast<const i32x4*>(coords + 4 * i);
        int cell = cr.x * GRIDC + cr.y + cr.z * NXD + cr.w;
        atomicOr(map + cell, (i + 1) | (npts[i] << NPTS_SHIFT));
    } else if (i < M + K) {
        int r = sel[i - M];
        i32x4 cr = *reinterpret_cast<const i32x4*>(coords + 4 * r);
        int cell = cr.x * GRIDC + cr.y + cr.z * NXD + cr.w;
        atomicOr(map + cell, SEL_FLAG);
    } else if (i < M + K + CD) {
        zerobuf[i - (M + K)] = 0.0f;
    }
}

// LINEAR-store one-pass fill (R5 structure, NT stores). Meta blocks at the
// FRONT of the grid so their 12MB overlap spatial ramp-up instead of forming
// a serial tail. Spatial block sbid owns the contiguous 4KB output span
// [sbid*1024, +1024) floats == (frame b, channel c, 1024 cells); thread t
// handles cells t*4 (wave-contiguous map loads and NT stores). Same-chunk
// blocks across channels differ by multiples of 256 blocks (and
// META_BLOCKS=1024), both ≡ 0 mod 8 -> same XCD -> map slice + feats rows
// are fetched ~once per XCD. NT stores keep the 4MB map L2-resident
// (R8 A/B: cached stores cost +6us via map eviction).
__global__ __launch_bounds__(256) void linear_fill_kernel(
        const float* __restrict__ feats,
        const int*   __restrict__ map,
        const float* __restrict__ zerobuf,
        float* __restrict__ out) {
    const int bid = blockIdx.x;
    const int t   = threadIdx.x;

    if (bid >= META_BLOCKS) {
        const int sbid = bid - META_BLOCKS;
        // sbid = ((b*64 + c) * 256 + chunk)
        const int b     = sbid >> 14;
        const int c     = (sbid >> 8) & 63;
        const int chunk = sbid & 255;
        const int cell0 = chunk * CELLS_PER_BLOCK + t * 4;    // within frame

        const i32x4 m4 = *reinterpret_cast<const i32x4*>(
            map + (size_t)b * GRIDC + cell0);
        const int rows[4] = {m4.x, m4.y, m4.z, m4.w};

        f32x4 v;
        #pragma unroll
        for (int j = 0; j < 4; ++j) {
            int m = rows[j];
            const float* p = (m & SEL_FLAG)
                ? (feats + ((size_t)((m & ROW_MASK) - 1) << 6))
                : zerobuf;
            v[j] = p[c];
        }
        __builtin_nontemporal_store(
            v, reinterpret_cast<f32x4*>(out + (size_t)sbid * CELLS_PER_BLOCK + t * 4));
    } else {
        // meta: occ / dens / pnum, each [B][GRIDC], after the spatial region
        const size_t cbase = (size_t)bid * CELLS_PER_BLOCK + t * 4;

        const i32x4 m4 = *reinterpret_cast<const i32x4*>(map + cbase);
        const int rows[4] = {m4.x, m4.y, m4.z, m4.w};

        const size_t spatial_elems = (size_t)BD * CD * GRIDC;
        const size_t map_elems     = (size_t)BD * GRIDC;
        float* __restrict__ occ  = out + spatial_elems;
        float* __restrict__ dens = occ + map_elems;
        float* __restrict__ pnum = dens + map_elems;

        f32x4 o, d, pn;
        #pragma unroll
        for (int j = 0; j < 4; ++j) {
            int m = rows[j];
            if (m != 0) {
                float n = (float)((m >> NPTS_SHIFT) & 63);
                o[j] = 1.0f;
                d[j] = n * (1.0f / 32.0f);
                pn[j] = n;
            } else {
                o[j] = 0.f; d[j] = 0.f; pn[j] = 0.f;
            }
        }
        __builtin_nontemporal_store(o,  reinterpret_cast<f32x4*>(occ  + cbase));
        __builtin_nontemporal_store(d,  reinterpret_cast<f32x4*>(dens + cbase));
        __builtin_nontemporal_store(pn, reinterpret_cast<f32x4*>(pnum + cbase));
    }
}

// ---------------- fallback path (used only if ws too small) ----------------

__global__ void scatter_meta_kernel(const int* __restrict__ coords,
                                    const int* __restrict__ npts,
                                    float* __restrict__ occ,
                                    float* __restrict__ dens,
                                    float* __restrict__ pnum,
                                    int M) {
    int i = blockIdx.x * blockDim.x + threadIdx.x;
    if (i >= M) return;
    int b = coords[4 * i + 0];
    int z = coords[4 * i + 1];
    int y = coords[4 * i + 2];
    int x = coords[4 * i + 3];
    int cell = b * GRIDC + z + y * NXD + x;
    float n = (float)npts[i];
    occ[cell]  = 1.0f;
    dens[cell] = n * (1.0f / 32.0f);
    pnum[cell] = n;
}

__global__ void scatter_spatial_kernel(const float* __restrict__ feats,
                                       const int* __restrict__ coords,
                                       const int* __restrict__ sel,
                                       float* __restrict__ spatial,
                                       int K) {
    int group = blockIdx.x * (blockDim.x >> 6) + (threadIdx.x >> 6);
    int c     = threadIdx.x & 63;
    if (group >= K) return;
    int row = sel[group];
    int b = coords[4 * row + 0];
    int z = coords[4 * row + 1];
    int y = coords[4 * row + 2];
    int x = coords[4 * row + 3];
    int cell = z + y * NXD + x;
    float v = feats[(size_t)row * CD + c];
    spatial[(size_t)b * ((size_t)CD * GRIDC) + (size_t)c * GRIDC + (size_t)cell] = v;
}

extern "C" void kernel_launch(void* const* d_in, const int* in_sizes, int n_in,
                              void* d_out, int out_size, void* d_ws, size_t ws_size,
                              hipStream_t stream) {
    const float* feats  = (const float*)d_in[0];  // [M, 64] f32
    const int*   coords = (const int*)d_in[1];    // [M, 4]  (b,z,y,x)
    const int*   npts   = (const int*)d_in[2];    // [M]
    const int*   sel    = (const int*)d_in[3];    // [K]

    const int M = in_sizes[2];
    const int K = in_sizes[3];

    float* out = (float*)d_out;
    const size_t map_bytes  = (size_t)BD * GRIDC * sizeof(int);  // 4 MB
    const size_t zero_bytes = CD * sizeof(float);                // 256 B

    if (ws_size >= map_bytes + zero_bytes) {
        int* map = (int*)d_ws;
        float* zerobuf = (float*)((char*)d_ws + map_bytes);
        (void)hipMemsetAsync(map, 0, map_bytes, stream);
        build_map_kernel<<<(M + K + CD + 255) / 256, 256, 0, stream>>>(
            coords, sel, npts, map, zerobuf, M, K);
        linear_fill_kernel<<<SPATIAL_BLOCKS + META_BLOCKS, 256, 0, stream>>>(
            feats, map, zerobuf, out);
    } else {
        // fallback: memset + scatter
        size_t spatial_elems = (size_t)BD * CD * GRIDC;
        size_t map_elems     = (size_t)BD * GRIDC;
        float* occ  = out + spatial_elems;
        float* dens = occ + map_elems;
        float* pnum = dens + map_elems;
        (void)hipMemsetAsync(d_out, 0, (size_t)out_size * sizeof(float), stream);
        scatter_meta_kernel<<<(M + 255) / 256, 256, 0, stream>>>(
            coords, npts, occ, dens, pnum, M);
        scatter_spatial_kernel<<<(K + 3) / 4, 256, 0, stream>>>(
            feats, coords, sel, out, K);
    }
}